// Round 6
// baseline (549.123 us; speedup 1.0000x reference)
//
#include <hip/hip_runtime.h>

#define N_NODES 50000
#define N_EDGES 3200000
#define N_GRAPHS 50
#define IN_F 5
#define HID 64
#define OUT_F 2

#define BKT_SHIFT 5
#define BKT_W 32                       // nodes per bucket
#define NBKT 1563                      // ceil(50000/32)
#define NB1 250                        // phase-1 blocks
#define EPB 12800                      // edges per phase-1 block (250*12800 = 3.2M exact)
#define CAP 2560                       // max edges per bucket (mean 2047, sigma 45 -> 11 sigma)
#define TILE_SHIFT 12                  // src tile = src>>12 (0..12), ~3.2MB of g per tile
#define NTILE 16                       // bins per node (13 used)
#define NBIN (BKT_W * NTILE)           // 512

// ---------- phase 1a: per-(bucket,block) histogram, LDS-aggregated ----------
__global__ void k_bhist(const int* dst, unsigned short* cw) {
    __shared__ int hist[NBKT];
    int t = threadIdx.x, blk = blockIdx.x;
    for (int b = t; b < NBKT; b += 256) hist[b] = 0;
    __syncthreads();
    int base = blk * EPB;
    for (int i = 0; i < EPB / 256; ++i) {
        int d = dst[base + i * 256 + t];
        atomicAdd(&hist[d >> BKT_SHIFT], 1);
    }
    __syncthreads();
    for (int b = t; b < NBKT; b += 256)
        cw[b * NB1 + blk] = (unsigned short)hist[b];
}

// ---------- phase 1b: per-bucket exclusive scan over the 250 block-counts ----------
__global__ void k_bscanA(unsigned short* cw, int* total) {
    __shared__ int s[256];
    int t = threadIdx.x, b = blockIdx.x;
    int v = (t < NB1) ? (int)cw[b * NB1 + t] : 0;
    s[t] = v;
    __syncthreads();
    for (int off = 1; off < 256; off <<= 1) {
        int a = (t >= off) ? s[t - off] : 0;
        __syncthreads();
        s[t] += a;
        __syncthreads();
    }
    if (t < NB1) cw[b * NB1 + t] = (unsigned short)(s[t] - v);  // in-place exclusive
    if (t == 255) total[b] = s[255];
}

// ---------- phase 1c: exclusive scan of 1563 bucket totals -> rpB ----------
__global__ void k_bscanB(const int* total, int* rpB) {
    __shared__ int s[256];
    int t = threadIdx.x;
    int v[7], sum = 0;
#pragma unroll
    for (int j = 0; j < 7; ++j) {
        int idx = t * 7 + j;
        v[j] = (idx < NBKT) ? total[idx] : 0;
        sum += v[j];
    }
    s[t] = sum;
    __syncthreads();
    for (int off = 1; off < 256; off <<= 1) {
        int a = (t >= off) ? s[t - off] : 0;
        __syncthreads();
        s[t] += a;
        __syncthreads();
    }
    int run = s[t] - sum;
#pragma unroll
    for (int j = 0; j < 7; ++j) {
        int idx = t * 7 + j;
        if (idx < NBKT) rpB[idx] = run;
        run += v[j];
    }
    if (t == 0) rpB[NBKT] = N_EDGES;
}

// ---------- phase 1d: write edges to bucket segments (payload: src | dl<<16, w) ----------
__global__ void k_bucket(const int* src, const int* dst, const float* ew,
                         const unsigned short* cw, const int* rpB, int2* bkt) {
    __shared__ int base[NBKT];
    __shared__ int off[NBKT];
    int t = threadIdx.x, blk = blockIdx.x;
    for (int b = t; b < NBKT; b += 256) {
        base[b] = (int)cw[b * NB1 + blk] + rpB[b];
        off[b] = 0;
    }
    __syncthreads();
    int ebase = blk * EPB;
    for (int i = 0; i < EPB / 256; ++i) {
        int idx = ebase + i * 256 + t;
        int d = dst[idx];
        int b = d >> BKT_SHIFT;
        int sl = base[b] + atomicAdd(&off[b], 1);
        bkt[sl] = make_int2(src[idx] | ((d & (BKT_W - 1)) << 16), __float_as_int(ew[idx]));
    }
}

// ---------- phase 2: 512-bin counting sort by (dst_local, src_tile); emits rp2 + dinv ----------
__global__ void k_bsort(const int* rpB, int2* bkt, int* rp2, float* dinv) {
    __shared__ int2 ebuf[CAP];          // 20 KB
    __shared__ int hist[NBIN];          // 2 KB
    __shared__ int binoff[NBIN];        // 2 KB (excl offsets, then cursors)
    __shared__ int s[256];
    __shared__ float wd[BKT_W];
    int t = threadIdx.x, b = blockIdx.x;
    int e0 = rpB[b], cnt = rpB[b + 1] - e0;
    for (int i = t; i < NBIN; i += 256) hist[i] = 0;
    if (t < BKT_W) wd[t] = 0.f;
    __syncthreads();
    for (int k = t; k < cnt; k += 256) {
        int2 e = bkt[e0 + k];
        ebuf[k] = e;
        int dl = (e.x >> 16) & (BKT_W - 1);
        int bin = (dl << 4) | ((e.x & 0xFFFF) >> TILE_SHIFT);
        atomicAdd(&hist[bin], 1);
        atomicAdd(&wd[dl], __int_as_float(e.y));
    }
    __syncthreads();
    // exclusive scan over 512 bins: pairwise partials + Hillis-Steele over 256
    int h0 = hist[2 * t], h1 = hist[2 * t + 1];
    int pv = h0 + h1;
    s[t] = pv;
    __syncthreads();
    for (int off = 1; off < 256; off <<= 1) {
        int a = (t >= off) ? s[t - off] : 0;
        __syncthreads();
        s[t] += a;
        __syncthreads();
    }
    int pe = s[t] - pv;                 // exclusive over pairs
    binoff[2 * t] = pe;
    binoff[2 * t + 1] = pe + h0;
    __syncthreads();
    if (t < BKT_W) {
        int node = (b << BKT_SHIFT) + t;
        if (node < N_NODES) {
            rp2[node] = e0 + binoff[t << 4];      // first bin of this dl
            dinv[node] = rsqrtf(1.0f + wd[t]);
        }
    }
    if (b == NBKT - 1 && t == 0) rp2[N_NODES] = N_EDGES;
    __syncthreads();                     // rp2 reads binoff before cursors mutate
    for (int k = t; k < cnt; k += 256) {
        int2 e = ebuf[k];
        int dl = (e.x >> 16) & (BKT_W - 1);
        int bin = (dl << 4) | ((e.x & 0xFFFF) >> TILE_SHIFT);
        int pos = atomicAdd(&binoff[bin], 1);
        bkt[e0 + pos] = make_int2(e.x & 0xFFFF, e.y);   // strip dl
    }
}

// ---------- layer-1 gather: p = di*(sum w*dinv[s]*x[s] + di*x[node]) ----------
__global__ void k_p(const int* rp2, const int2* bkt, const float* dinv,
                    const float* x, float* p) {
    int node = blockIdx.x * 4 + (threadIdx.x >> 6);
    int lane = threadIdx.x & 63;
    if (node >= N_NODES) return;
    int b = rp2[node], en = rp2[node + 1];
    float a0 = 0.f, a1 = 0.f, a2 = 0.f, a3 = 0.f, a4 = 0.f;
    for (int k = b + lane; k < en; k += 64) {
        int2 ev = bkt[k];
        int s = ev.x;
        float n = dinv[s] * __int_as_float(ev.y);
        const float* xs = &x[s * IN_F];
        a0 += xs[0] * n; a1 += xs[1] * n; a2 += xs[2] * n; a3 += xs[3] * n; a4 += xs[4] * n;
    }
    for (int off = 32; off; off >>= 1) {
        a0 += __shfl_down(a0, off); a1 += __shfl_down(a1, off); a2 += __shfl_down(a2, off);
        a3 += __shfl_down(a3, off); a4 += __shfl_down(a4, off);
    }
    if (lane == 0) {
        float di = dinv[node];
        const float* xi = &x[node * IN_F];
        float* pp = &p[node * IN_F];
        pp[0] = di * (a0 + di * xi[0]); pp[1] = di * (a1 + di * xi[1]);
        pp[2] = di * (a2 + di * xi[2]); pp[3] = di * (a3 + di * xi[3]);
        pp[4] = di * (a4 + di * xi[4]);
    }
}

// ---------- fused h1 = relu(p@W1+b1); g' = (h1@W2)*dinv ----------
__global__ void k_h1g(const float* p, const float* W1, const float* b1,
                      const float* W2, const float* dinv, float* g) {
    __shared__ float W1s[IN_F * HID];
    __shared__ float W2s[HID * HID];
    __shared__ float b1s[HID];
    int t = threadIdx.x;
    for (int k = t; k < IN_F * HID; k += 256) W1s[k] = W1[k];
    for (int k = t; k < HID * HID; k += 256) W2s[k] = W2[k];
    if (t < HID) b1s[t] = b1[t];
    __syncthreads();
    int lane = t & 63;
    int wid = blockIdx.x * 4 + (t >> 6);
    int nw = gridDim.x * 4;
    for (int node = wid; node < N_NODES; node += nw) {
        const float* pp = &p[node * IN_F];
        float pv0 = pp[0], pv1 = pp[1], pv2 = pp[2], pv3 = pp[3], pv4 = pp[4];
        float h = b1s[lane] + pv0 * W1s[lane] + pv1 * W1s[64 + lane] + pv2 * W1s[128 + lane]
                + pv3 * W1s[192 + lane] + pv4 * W1s[256 + lane];
        h = fmaxf(h, 0.f);
        float acc = 0.f;
#pragma unroll
        for (int f = 0; f < HID; ++f)
            acc += __shfl(h, f) * W2s[f * HID + lane];
        g[node * HID + lane] = acc * dinv[node];   // pre-scaled by dinv
    }
}

// ---------- layer-2 gather (16-deep MLP) fused with bias/relu/pool ----------
#define CHUNK 4
__global__ __launch_bounds__(256, 8) void k_h2g(const int* rp2, const int2* bkt,
                      const float* dinv, const float* g, const float* b2,
                      const int* batch, float* pool) {
    int t = threadIdx.x, lane = t & 63;
    int wid = blockIdx.x * 4 + (t >> 6);
    int n0 = wid * CHUNK;
    if (n0 >= N_NODES) return;
    int n1 = min(n0 + CHUNK, N_NODES);
    float bj = b2[lane];
    float accp = 0.f;
    int cur = batch[n0];
    for (int node = n0; node < n1; ++node) {
        int k0 = rp2[node], e1 = rp2[node + 1];
        float acc = g[node * HID + lane];          // self-loop (g' = g*dinv)
        for (; k0 + 64 <= e1; k0 += 64) {
            int2 ev = bkt[k0 + lane];
#pragma unroll
            for (int q = 0; q < 4; ++q) {
                float vv[16], ww[16];
#pragma unroll
                for (int j = 0; j < 16; ++j) {
                    int sx = __shfl(ev.x, q * 16 + j);
                    ww[j] = __int_as_float(__shfl(ev.y, q * 16 + j));
                    vv[j] = g[sx * HID + lane];
                }
#pragma unroll
                for (int j = 0; j < 16; ++j) acc += vv[j] * ww[j];
            }
        }
        if (k0 < e1) {
            int kk = k0 + lane;
            int2 ev = (kk < e1) ? bkt[kk] : make_int2(0, 0);
            int m = e1 - k0;
            for (int tt = 0; tt < m; ++tt) {
                int sx = __shfl(ev.x, tt);
                float w = __int_as_float(__shfl(ev.y, tt));
                acc += g[sx * HID + lane] * w;
            }
        }
        float h2 = fmaxf(dinv[node] * acc + bj, 0.f);
        int bb = batch[node];
        if (bb != cur) {
            atomicAdd(&pool[cur * HID + lane], accp);
            cur = bb;
            accp = 0.f;
        }
        accp += h2;
    }
    atomicAdd(&pool[cur * HID + lane], accp);
}

__device__ int lowb(const int* a, int n, int v) {
    int lo = 0, hi = n;
    while (lo < hi) { int m = (lo + hi) >> 1; if (a[m] < v) lo = m + 1; else hi = m; }
    return lo;
}

__global__ void k_out(const float* pool, const int* batch, const float* Wo,
                      const float* bo, float* out) {
    int t = blockIdx.x * blockDim.x + threadIdx.x;
    if (t < N_GRAPHS * OUT_F) {
        int gi = t / OUT_F, k = t % OUT_F;
        int c = lowb(batch, N_NODES, gi + 1) - lowb(batch, N_NODES, gi);
        float cf = fmaxf((float)c, 1.0f);
        float acc = bo[k];
        for (int f = 0; f < HID; ++f)
            acc += (pool[gi * HID + f] / cf) * Wo[f * OUT_F + k];
        out[t] = acc;
    }
}

extern "C" void kernel_launch(void* const* d_in, const int* in_sizes, int n_in,
                              void* d_out, int out_size, void* d_ws, size_t ws_size,
                              hipStream_t stream) {
    const float* x   = (const float*)d_in[0];
    const int*   ei  = (const int*)d_in[1];
    const float* ea  = (const float*)d_in[2];
    const int*   bat = (const int*)d_in[3];
    const float* W1  = (const float*)d_in[4];
    const float* b1  = (const float*)d_in[5];
    const float* W2  = (const float*)d_in[6];
    const float* b2  = (const float*)d_in[7];
    const float* Wo  = (const float*)d_in[8];
    const float* bo  = (const float*)d_in[9];
    float* out = (float*)d_out;

    const int* src = ei;
    const int* dst = ei + N_EDGES;

    // workspace layout (float units) — total 9,954,800 floats = 39.8 MB
    float* ws = (float*)d_ws;
    int*   rpB   = (int*)ws;                         // 1564 (pad 1568)
    int*   rp2   = (int*)(ws + 1568);                // 50001 (pad 50016)
    float* dinv  = ws + 51584;                       // 50000 (pad 50016)
    float* pool  = ws + 101600;                      // 3200
    int*   total = (int*)(ws + 101600);              // 1563, overlays pool, dead after bscanB
    unsigned short* cw = (unsigned short*)(ws + 104800);  // 390750 u16 = 195375 fl, dead after k_bucket
    float* p     = ws + 104800;                      // 250000, overlays cw, written after
    int2*  bkt   = (int2*)(ws + 354800);             // 3.2M int2 = 6.4M floats
    float* g     = ws + 6754800;                     // 3.2M

    k_bhist <<<NB1, 256, 0, stream>>>(dst, cw);
    k_bscanA<<<NBKT, 256, 0, stream>>>(cw, total);
    k_bscanB<<<1, 256, 0, stream>>>(total, rpB);
    hipMemsetAsync(pool, 0, N_GRAPHS * HID * sizeof(float), stream);  // after bscanB (total overlays pool)
    k_bucket<<<NB1, 256, 0, stream>>>(src, dst, ea, cw, rpB, bkt);
    k_bsort <<<NBKT, 256, 0, stream>>>(rpB, bkt, rp2, dinv);
    k_p     <<<(N_NODES + 3) / 4, 256, 0, stream>>>(rp2, bkt, dinv, x, p);
    k_h1g   <<<1024, 256, 0, stream>>>(p, W1, b1, W2, dinv, g);
    k_h2g   <<<(N_NODES + 4 * CHUNK - 1) / (4 * CHUNK), 256, 0, stream>>>(rp2, bkt, dinv, g, b2, bat, pool);
    k_out   <<<1, 128, 0, stream>>>(pool, bat, Wo, bo, out);
}

// Round 7
// 402.023 us; speedup vs baseline: 1.3659x; 1.3659x over previous
//
#include <hip/hip_runtime.h>
#include <hip/hip_fp16.h>

#define N_NODES 50000
#define N_EDGES 3200000
#define N_GRAPHS 50
#define IN_F 5
#define HID 64
#define OUT_F 2

#define BKT_SHIFT 5
#define BKT_W 32                       // nodes per bucket
#define NBKT 1563                      // ceil(50000/32)
#define NB1 250                        // phase-1 blocks
#define EPB 12800                      // edges per phase-1 block (250*12800 = 3.2M exact)
#define CAP 2560                       // max edges per bucket (mean 2047, sigma 45 -> 11 sigma)
#define TILE_SHIFT 12                  // src tile = src>>12 (0..12)
#define NTILE 16                       // bins per node (13 used)
#define NBIN (BKT_W * NTILE)           // 512

// ---------- phase 1a: per-(bucket,block) histogram, LDS-aggregated ----------
__global__ void k_bhist(const int* dst, unsigned short* cw) {
    __shared__ int hist[NBKT];
    int t = threadIdx.x, blk = blockIdx.x;
    for (int b = t; b < NBKT; b += 256) hist[b] = 0;
    __syncthreads();
    int base = blk * EPB;
    for (int i = 0; i < EPB / 256; ++i) {
        int d = dst[base + i * 256 + t];
        atomicAdd(&hist[d >> BKT_SHIFT], 1);
    }
    __syncthreads();
    for (int b = t; b < NBKT; b += 256)
        cw[b * NB1 + blk] = (unsigned short)hist[b];
}

// ---------- phase 1b: per-bucket exclusive scan over the 250 block-counts ----------
__global__ void k_bscanA(unsigned short* cw, int* total) {
    __shared__ int s[256];
    int t = threadIdx.x, b = blockIdx.x;
    int v = (t < NB1) ? (int)cw[b * NB1 + t] : 0;
    s[t] = v;
    __syncthreads();
    for (int off = 1; off < 256; off <<= 1) {
        int a = (t >= off) ? s[t - off] : 0;
        __syncthreads();
        s[t] += a;
        __syncthreads();
    }
    if (t < NB1) cw[b * NB1 + t] = (unsigned short)(s[t] - v);  // in-place exclusive
    if (t == 255) total[b] = s[255];
}

// ---------- phase 1c: exclusive scan of 1563 bucket totals -> rpB ----------
__global__ void k_bscanB(const int* total, int* rpB) {
    __shared__ int s[256];
    int t = threadIdx.x;
    int v[7], sum = 0;
#pragma unroll
    for (int j = 0; j < 7; ++j) {
        int idx = t * 7 + j;
        v[j] = (idx < NBKT) ? total[idx] : 0;
        sum += v[j];
    }
    s[t] = sum;
    __syncthreads();
    for (int off = 1; off < 256; off <<= 1) {
        int a = (t >= off) ? s[t - off] : 0;
        __syncthreads();
        s[t] += a;
        __syncthreads();
    }
    int run = s[t] - sum;
#pragma unroll
    for (int j = 0; j < 7; ++j) {
        int idx = t * 7 + j;
        if (idx < NBKT) rpB[idx] = run;
        run += v[j];
    }
    if (t == 0) rpB[NBKT] = N_EDGES;
}

// ---------- phase 1d: write edges to bucket segments (payload: src | dl<<16, w) ----------
__global__ void k_bucket(const int* src, const int* dst, const float* ew,
                         const unsigned short* cw, const int* rpB, int2* bkt) {
    __shared__ int base[NBKT];
    __shared__ int off[NBKT];
    int t = threadIdx.x, blk = blockIdx.x;
    for (int b = t; b < NBKT; b += 256) {
        base[b] = (int)cw[b * NB1 + blk] + rpB[b];
        off[b] = 0;
    }
    __syncthreads();
    int ebase = blk * EPB;
    for (int i = 0; i < EPB / 256; ++i) {
        int idx = ebase + i * 256 + t;
        int d = dst[idx];
        int b = d >> BKT_SHIFT;
        int sl = base[b] + atomicAdd(&off[b], 1);
        bkt[sl] = make_int2(src[idx] | ((d & (BKT_W - 1)) << 16), __float_as_int(ew[idx]));
    }
}

// ---------- phase 2: 512-bin counting sort by (dst_local, src_tile); emits rp2 + dinv ----------
__global__ void k_bsort(const int* rpB, int2* bkt, int* rp2, float* dinv) {
    __shared__ int2 ebuf[CAP];          // 20 KB
    __shared__ int hist[NBIN];          // 2 KB
    __shared__ int binoff[NBIN];        // 2 KB (excl offsets, then cursors)
    __shared__ int s[256];
    __shared__ float wd[BKT_W];
    int t = threadIdx.x, b = blockIdx.x;
    int e0 = rpB[b], cnt = rpB[b + 1] - e0;
    for (int i = t; i < NBIN; i += 256) hist[i] = 0;
    if (t < BKT_W) wd[t] = 0.f;
    __syncthreads();
    for (int k = t; k < cnt; k += 256) {
        int2 e = bkt[e0 + k];
        ebuf[k] = e;
        int dl = (e.x >> 16) & (BKT_W - 1);
        int bin = (dl << 4) | ((e.x & 0xFFFF) >> TILE_SHIFT);
        atomicAdd(&hist[bin], 1);
        atomicAdd(&wd[dl], __int_as_float(e.y));
    }
    __syncthreads();
    // exclusive scan over 512 bins: pairwise partials + Hillis-Steele over 256
    int h0 = hist[2 * t], h1 = hist[2 * t + 1];
    int pv = h0 + h1;
    s[t] = pv;
    __syncthreads();
    for (int off = 1; off < 256; off <<= 1) {
        int a = (t >= off) ? s[t - off] : 0;
        __syncthreads();
        s[t] += a;
        __syncthreads();
    }
    int pe = s[t] - pv;                 // exclusive over pairs
    binoff[2 * t] = pe;
    binoff[2 * t + 1] = pe + h0;
    __syncthreads();
    if (t < BKT_W) {
        int node = (b << BKT_SHIFT) + t;
        if (node < N_NODES) {
            rp2[node] = e0 + binoff[t << 4];      // first bin of this dl
            dinv[node] = rsqrtf(1.0f + wd[t]);
        }
    }
    if (b == NBKT - 1 && t == 0) rp2[N_NODES] = N_EDGES;
    __syncthreads();                     // rp2 reads binoff before cursors mutate
    for (int k = t; k < cnt; k += 256) {
        int2 e = ebuf[k];
        int dl = (e.x >> 16) & (BKT_W - 1);
        int bin = (dl << 4) | ((e.x & 0xFFFF) >> TILE_SHIFT);
        int pos = atomicAdd(&binoff[bin], 1);
        bkt[e0 + pos] = make_int2(e.x & 0xFFFF, e.y);   // strip dl
    }
}

// ---------- layer-1 gather: p = di*(sum w*dinv[s]*x[s] + di*x[node]) ----------
__global__ void k_p(const int* rp2, const int2* bkt, const float* dinv,
                    const float* x, float* p) {
    int node = blockIdx.x * 4 + (threadIdx.x >> 6);
    int lane = threadIdx.x & 63;
    if (node >= N_NODES) return;
    int b = rp2[node], en = rp2[node + 1];
    float a0 = 0.f, a1 = 0.f, a2 = 0.f, a3 = 0.f, a4 = 0.f;
    for (int k = b + lane; k < en; k += 64) {
        int2 ev = bkt[k];
        int s = ev.x;
        float n = dinv[s] * __int_as_float(ev.y);
        const float* xs = &x[s * IN_F];
        a0 += xs[0] * n; a1 += xs[1] * n; a2 += xs[2] * n; a3 += xs[3] * n; a4 += xs[4] * n;
    }
    for (int off = 32; off; off >>= 1) {
        a0 += __shfl_down(a0, off); a1 += __shfl_down(a1, off); a2 += __shfl_down(a2, off);
        a3 += __shfl_down(a3, off); a4 += __shfl_down(a4, off);
    }
    if (lane == 0) {
        float di = dinv[node];
        const float* xi = &x[node * IN_F];
        float* pp = &p[node * IN_F];
        pp[0] = di * (a0 + di * xi[0]); pp[1] = di * (a1 + di * xi[1]);
        pp[2] = di * (a2 + di * xi[2]); pp[3] = di * (a3 + di * xi[3]);
        pp[4] = di * (a4 + di * xi[4]);
    }
}

// ---------- fused h1 = relu(p@W1+b1); g' = fp16((h1@W2)*dinv) ----------
__global__ void k_h1g(const float* p, const float* W1, const float* b1,
                      const float* W2, const float* dinv, __half* g) {
    __shared__ float W1s[IN_F * HID];
    __shared__ float W2s[HID * HID];
    __shared__ float b1s[HID];
    int t = threadIdx.x;
    for (int k = t; k < IN_F * HID; k += 256) W1s[k] = W1[k];
    for (int k = t; k < HID * HID; k += 256) W2s[k] = W2[k];
    if (t < HID) b1s[t] = b1[t];
    __syncthreads();
    int lane = t & 63;
    int wid = blockIdx.x * 4 + (t >> 6);
    int nw = gridDim.x * 4;
    for (int node = wid; node < N_NODES; node += nw) {
        const float* pp = &p[node * IN_F];
        float pv0 = pp[0], pv1 = pp[1], pv2 = pp[2], pv3 = pp[3], pv4 = pp[4];
        float h = b1s[lane] + pv0 * W1s[lane] + pv1 * W1s[64 + lane] + pv2 * W1s[128 + lane]
                + pv3 * W1s[192 + lane] + pv4 * W1s[256 + lane];
        h = fmaxf(h, 0.f);
        float acc = 0.f;
#pragma unroll
        for (int f = 0; f < HID; ++f) {
            float hf = __int_as_float(__builtin_amdgcn_readlane(__float_as_int(h), f));
            acc += hf * W2s[f * HID + lane];
        }
        g[node * HID + lane] = __float2half(acc * dinv[node]);   // pre-scaled by dinv
    }
}

// ---------- layer-2 gather (16-deep, readlane broadcast) fused with bias/relu/pool ----------
#define CHUNK 4
__global__ __launch_bounds__(256, 8) void k_h2g(const int* rp2, const int2* bkt,
                      const float* dinv, const __half* g, const float* b2,
                      const int* batch, float* pool) {
    int t = threadIdx.x, lane = t & 63;
    int wid = blockIdx.x * 4 + (t >> 6);
    int n0 = wid * CHUNK;
    if (n0 >= N_NODES) return;
    int n1 = min(n0 + CHUNK, N_NODES);
    float bj = b2[lane];
    float accp = 0.f;
    int cur = batch[n0];
    for (int node = n0; node < n1; ++node) {
        int k0 = rp2[node], e1 = rp2[node + 1];
        float acc = __half2float(g[node * HID + lane]);   // self-loop (g' = g*dinv)
        for (; k0 + 64 <= e1; k0 += 64) {
            int2 ev = bkt[k0 + lane];
#pragma unroll
            for (int q = 0; q < 4; ++q) {
                float vv[16], ww[16];
#pragma unroll
                for (int j = 0; j < 16; ++j) {
                    int sx = __builtin_amdgcn_readlane(ev.x, q * 16 + j);
                    ww[j] = __int_as_float(__builtin_amdgcn_readlane(ev.y, q * 16 + j));
                    vv[j] = __half2float(g[sx * HID + lane]);
                }
#pragma unroll
                for (int j = 0; j < 16; ++j) acc += vv[j] * ww[j];
            }
        }
        if (k0 < e1) {
            int kk = k0 + lane;
            int2 ev = (kk < e1) ? bkt[kk] : make_int2(0, 0);
            int m = e1 - k0;
            for (int tt = 0; tt < m; ++tt) {
                int sx = __builtin_amdgcn_readlane(ev.x, tt);
                float w = __int_as_float(__builtin_amdgcn_readlane(ev.y, tt));
                acc += __half2float(g[sx * HID + lane]) * w;
            }
        }
        float h2 = fmaxf(dinv[node] * acc + bj, 0.f);
        int bb = batch[node];
        if (bb != cur) {
            atomicAdd(&pool[cur * HID + lane], accp);
            cur = bb;
            accp = 0.f;
        }
        accp += h2;
    }
    atomicAdd(&pool[cur * HID + lane], accp);
}

__device__ int lowb(const int* a, int n, int v) {
    int lo = 0, hi = n;
    while (lo < hi) { int m = (lo + hi) >> 1; if (a[m] < v) lo = m + 1; else hi = m; }
    return lo;
}

__global__ void k_out(const float* pool, const int* batch, const float* Wo,
                      const float* bo, float* out) {
    int t = blockIdx.x * blockDim.x + threadIdx.x;
    if (t < N_GRAPHS * OUT_F) {
        int gi = t / OUT_F, k = t % OUT_F;
        int c = lowb(batch, N_NODES, gi + 1) - lowb(batch, N_NODES, gi);
        float cf = fmaxf((float)c, 1.0f);
        float acc = bo[k];
        for (int f = 0; f < HID; ++f)
            acc += (pool[gi * HID + f] / cf) * Wo[f * OUT_F + k];
        out[t] = acc;
    }
}

extern "C" void kernel_launch(void* const* d_in, const int* in_sizes, int n_in,
                              void* d_out, int out_size, void* d_ws, size_t ws_size,
                              hipStream_t stream) {
    const float* x   = (const float*)d_in[0];
    const int*   ei  = (const int*)d_in[1];
    const float* ea  = (const float*)d_in[2];
    const int*   bat = (const int*)d_in[3];
    const float* W1  = (const float*)d_in[4];
    const float* b1  = (const float*)d_in[5];
    const float* W2  = (const float*)d_in[6];
    const float* b2  = (const float*)d_in[7];
    const float* Wo  = (const float*)d_in[8];
    const float* bo  = (const float*)d_in[9];
    float* out = (float*)d_out;

    const int* src = ei;
    const int* dst = ei + N_EDGES;

    // workspace layout (float units)
    float* ws = (float*)d_ws;
    int*   rpB   = (int*)ws;                         // 1564 (pad 1568)
    int*   rp2   = (int*)(ws + 1568);                // 50001 (pad 50016)
    float* dinv  = ws + 51584;                       // 50000 (pad 50016)
    float* pool  = ws + 101600;                      // 3200
    int*   total = (int*)(ws + 101600);              // 1563, overlays pool, dead after bscanB
    unsigned short* cw = (unsigned short*)(ws + 104800);  // 390750 u16, dead after k_bucket
    float* p     = ws + 104800;                      // 250000, overlays cw, written after
    int2*  bkt   = (int2*)(ws + 354800);             // 3.2M int2 = 6.4M floats
    __half* g    = (__half*)(ws + 6754800);          // 3.2M halves = 1.6M floats

    k_bhist <<<NB1, 256, 0, stream>>>(dst, cw);
    k_bscanA<<<NBKT, 256, 0, stream>>>(cw, total);
    k_bscanB<<<1, 256, 0, stream>>>(total, rpB);
    hipMemsetAsync(pool, 0, N_GRAPHS * HID * sizeof(float), stream);  // after bscanB (total overlays pool)
    k_bucket<<<NB1, 256, 0, stream>>>(src, dst, ea, cw, rpB, bkt);
    k_bsort <<<NBKT, 256, 0, stream>>>(rpB, bkt, rp2, dinv);
    k_p     <<<(N_NODES + 3) / 4, 256, 0, stream>>>(rp2, bkt, dinv, x, p);
    k_h1g   <<<1024, 256, 0, stream>>>(p, W1, b1, W2, dinv, g);
    k_h2g   <<<(N_NODES + 4 * CHUNK - 1) / (4 * CHUNK), 256, 0, stream>>>(rp2, bkt, dinv, g, b2, bat, pool);
    k_out   <<<1, 128, 0, stream>>>(pool, bat, Wo, bo, out);
}

// Round 8
// 336.383 us; speedup vs baseline: 1.6324x; 1.1951x over previous
//
#include <hip/hip_runtime.h>
#include <hip/hip_fp16.h>

#define N_NODES 50000
#define N_EDGES 3200000
#define N_GRAPHS 50
#define IN_F 5
#define HID 64
#define OUT_F 2

#define BKT_SHIFT 5
#define BKT_W 32                       // nodes per bucket
#define NBKT 1563                      // ceil(50000/32)
#define NB1 250                        // phase-1 blocks
#define EPB 12800                      // edges per phase-1 block (250*12800 = 3.2M exact)
#define CAP 2560                       // max edges per bucket (mean 2047, sigma 45 -> 11 sigma)
#define TILE_SHIFT 12                  // src tile = src>>12 (0..12)
#define NTILE 16                       // bins per node (13 used)
#define NBIN (BKT_W * NTILE)           // 512
#define NWAVE 8192                     // k_h2g waves (2048 blocks, all co-resident)

// ---------- phase 1a: per-(bucket,block) histogram, LDS-aggregated ----------
__global__ void k_bhist(const int* dst, unsigned short* cw) {
    __shared__ int hist[NBKT];
    int t = threadIdx.x, blk = blockIdx.x;
    for (int b = t; b < NBKT; b += 256) hist[b] = 0;
    __syncthreads();
    int base = blk * EPB;
    for (int i = 0; i < EPB / 256; ++i) {
        int d = dst[base + i * 256 + t];
        atomicAdd(&hist[d >> BKT_SHIFT], 1);
    }
    __syncthreads();
    for (int b = t; b < NBKT; b += 256)
        cw[b * NB1 + blk] = (unsigned short)hist[b];
}

// ---------- phase 1b: per-bucket exclusive scan over the 250 block-counts ----------
__global__ void k_bscanA(unsigned short* cw, int* total) {
    __shared__ int s[256];
    int t = threadIdx.x, b = blockIdx.x;
    int v = (t < NB1) ? (int)cw[b * NB1 + t] : 0;
    s[t] = v;
    __syncthreads();
    for (int off = 1; off < 256; off <<= 1) {
        int a = (t >= off) ? s[t - off] : 0;
        __syncthreads();
        s[t] += a;
        __syncthreads();
    }
    if (t < NB1) cw[b * NB1 + t] = (unsigned short)(s[t] - v);  // in-place exclusive
    if (t == 255) total[b] = s[255];
}

// ---------- phase 1c: exclusive scan of 1563 bucket totals -> rpB ----------
__global__ void k_bscanB(const int* total, int* rpB) {
    __shared__ int s[256];
    int t = threadIdx.x;
    int v[7], sum = 0;
#pragma unroll
    for (int j = 0; j < 7; ++j) {
        int idx = t * 7 + j;
        v[j] = (idx < NBKT) ? total[idx] : 0;
        sum += v[j];
    }
    s[t] = sum;
    __syncthreads();
    for (int off = 1; off < 256; off <<= 1) {
        int a = (t >= off) ? s[t - off] : 0;
        __syncthreads();
        s[t] += a;
        __syncthreads();
    }
    int run = s[t] - sum;
#pragma unroll
    for (int j = 0; j < 7; ++j) {
        int idx = t * 7 + j;
        if (idx < NBKT) rpB[idx] = run;
        run += v[j];
    }
    if (t == 0) rpB[NBKT] = N_EDGES;
}

// ---------- phase 1d: write edges to bucket segments (payload: src | dl<<16, fp32 w) ----------
__global__ void k_bucket(const int* src, const int* dst, const float* ew,
                         const unsigned short* cw, const int* rpB, int2* bkt) {
    __shared__ int base[NBKT];
    __shared__ int off[NBKT];
    int t = threadIdx.x, blk = blockIdx.x;
    for (int b = t; b < NBKT; b += 256) {
        base[b] = (int)cw[b * NB1 + blk] + rpB[b];
        off[b] = 0;
    }
    __syncthreads();
    int ebase = blk * EPB;
    for (int i = 0; i < EPB / 256; ++i) {
        int idx = ebase + i * 256 + t;
        int d = dst[idx];
        int b = d >> BKT_SHIFT;
        int sl = base[b] + atomicAdd(&off[b], 1);
        bkt[sl] = make_int2(src[idx] | ((d & (BKT_W - 1)) << 16), __float_as_int(ew[idx]));
    }
}

// ---------- phase 2: 512-bin sort by (dst_local, src_tile); in-place 4B compaction ----------
// Output: packed int stream {u16 src | fp16 w} at int-index [rp2[node], rp2e[node])
__global__ void k_bsort(const int* rpB, int2* bkt, int* rp2, int* rp2e, float* dinv) {
    __shared__ int2 ebuf[CAP];          // 20 KB
    __shared__ int hist[NBIN];          // 2 KB
    __shared__ int binoff[NBIN];        // 2 KB (excl offsets, then cursors)
    __shared__ int s[256];
    __shared__ float wd[BKT_W];
    int t = threadIdx.x, b = blockIdx.x;
    int e0 = rpB[b], cnt = rpB[b + 1] - e0;
    for (int i = t; i < NBIN; i += 256) hist[i] = 0;
    if (t < BKT_W) wd[t] = 0.f;
    __syncthreads();
    for (int k = t; k < cnt; k += 256) {
        int2 e = bkt[e0 + k];
        ebuf[k] = e;
        int dl = (e.x >> 16) & (BKT_W - 1);
        int bin = (dl << 4) | ((e.x & 0xFFFF) >> TILE_SHIFT);
        atomicAdd(&hist[bin], 1);
        atomicAdd(&wd[dl], __int_as_float(e.y));
    }
    __syncthreads();
    // exclusive scan over 512 bins: pairwise partials + Hillis-Steele over 256
    int h0 = hist[2 * t], h1 = hist[2 * t + 1];
    int pv = h0 + h1;
    s[t] = pv;
    __syncthreads();
    for (int off = 1; off < 256; off <<= 1) {
        int a = (t >= off) ? s[t - off] : 0;
        __syncthreads();
        s[t] += a;
        __syncthreads();
    }
    int pe = s[t] - pv;                 // exclusive over pairs
    binoff[2 * t] = pe;
    binoff[2 * t + 1] = pe + h0;
    __syncthreads();
    if (t < BKT_W) {
        int node = (b << BKT_SHIFT) + t;
        if (node < N_NODES) {
            int startl = binoff[t << 4];
            int endl = (t == BKT_W - 1) ? cnt : binoff[(t + 1) << 4];
            rp2[node]  = 2 * e0 + startl;
            rp2e[node] = 2 * e0 + endl;
            dinv[node] = rsqrtf(1.0f + wd[t]);
        }
    }
    __syncthreads();                     // rp2/rp2e read binoff before cursors mutate
    for (int k = t; k < cnt; k += 256) {
        int2 e = ebuf[k];
        int dl = (e.x >> 16) & (BKT_W - 1);
        int bin = (dl << 4) | ((e.x & 0xFFFF) >> TILE_SHIFT);
        int pos = atomicAdd(&binoff[bin], 1);
        unsigned short wh = __half_as_ushort(__float2half(__int_as_float(e.y)));
        ((int*)bkt)[2 * e0 + pos] = (e.x & 0xFFFF) | ((int)wh << 16);
    }
}

// ---------- xp[i][0..7] = fp16(x[i][f] * dinv[i]) (800KB, L2-resident) ----------
__global__ void k_xprep(const float* x, const float* dinv, __half* xp) {
    int i = blockIdx.x * 256 + threadIdx.x;
    if (i < N_NODES) {
        float di = dinv[i];
        const float* xi = &x[i * IN_F];
        __half* o = &xp[i * 8];
#pragma unroll
        for (int f = 0; f < IN_F; ++f) o[f] = __float2half(xi[f] * di);
        o[5] = o[6] = o[7] = __float2half(0.f);
    }
}

// ---------- layer-1 gather: p = di*(sum w*xp[s] + xp[node]) ----------
__global__ void k_p(const int* rp2, const int* rp2e, const int* pk,
                    const __half* xp, const float* dinv, float* p) {
    int node = blockIdx.x * 4 + (threadIdx.x >> 6);
    int lane = threadIdx.x & 63;
    if (node >= N_NODES) return;
    int b = rp2[node], en = rp2e[node];
    float a0 = 0.f, a1 = 0.f, a2 = 0.f, a3 = 0.f, a4 = 0.f;
    for (int k = b + lane; k < en; k += 64) {
        int e = pk[k];
        float w = __half2float(__ushort_as_half((unsigned short)((unsigned)e >> 16)));
        const __half* xs = &xp[(e & 0xFFFF) * 8];
        int4 xv = *reinterpret_cast<const int4*>(xs);
        __half2 p01 = *(__half2*)&xv.x;
        __half2 p23 = *(__half2*)&xv.y;
        __half2 p45 = *(__half2*)&xv.z;
        a0 += w * __half2float(p01.x); a1 += w * __half2float(p01.y);
        a2 += w * __half2float(p23.x); a3 += w * __half2float(p23.y);
        a4 += w * __half2float(p45.x);
    }
    for (int off = 32; off; off >>= 1) {
        a0 += __shfl_down(a0, off); a1 += __shfl_down(a1, off); a2 += __shfl_down(a2, off);
        a3 += __shfl_down(a3, off); a4 += __shfl_down(a4, off);
    }
    if (lane == 0) {
        float di = dinv[node];
        const __half* xn = &xp[node * 8];
        float* pp = &p[node * IN_F];
        pp[0] = di * (a0 + __half2float(xn[0]));
        pp[1] = di * (a1 + __half2float(xn[1]));
        pp[2] = di * (a2 + __half2float(xn[2]));
        pp[3] = di * (a3 + __half2float(xn[3]));
        pp[4] = di * (a4 + __half2float(xn[4]));
    }
}

// ---------- fused h1 = relu(p@W1+b1); g' = fp16((h1@W2)*dinv) ----------
__global__ void k_h1g(const float* p, const float* W1, const float* b1,
                      const float* W2, const float* dinv, __half* g) {
    __shared__ float W1s[IN_F * HID];
    __shared__ float W2s[HID * HID];
    __shared__ float b1s[HID];
    int t = threadIdx.x;
    for (int k = t; k < IN_F * HID; k += 256) W1s[k] = W1[k];
    for (int k = t; k < HID * HID; k += 256) W2s[k] = W2[k];
    if (t < HID) b1s[t] = b1[t];
    __syncthreads();
    int lane = t & 63;
    int wid = blockIdx.x * 4 + (t >> 6);
    int nw = gridDim.x * 4;
    for (int node = wid; node < N_NODES; node += nw) {
        const float* pp = &p[node * IN_F];
        float pv0 = pp[0], pv1 = pp[1], pv2 = pp[2], pv3 = pp[3], pv4 = pp[4];
        float h = b1s[lane] + pv0 * W1s[lane] + pv1 * W1s[64 + lane] + pv2 * W1s[128 + lane]
                + pv3 * W1s[192 + lane] + pv4 * W1s[256 + lane];
        h = fmaxf(h, 0.f);
        float acc = 0.f;
#pragma unroll
        for (int f = 0; f < HID; ++f) {
            float hf = __int_as_float(__builtin_amdgcn_readlane(__float_as_int(h), f));
            acc += hf * W2s[f * HID + lane];
        }
        g[node * HID + lane] = __float2half(acc * dinv[node]);   // pre-scaled by dinv
    }
}

// ---------- layer-2 gather (16-deep for ALL edges) fused with bias/relu/pool ----------
__global__ __launch_bounds__(256, 8) void k_h2g(const int* rp2, const int* rp2e,
                      const int* pk, const float* dinv, const __half* g,
                      const float* b2, const int* batch, float* pool) {
    int t = threadIdx.x, lane = t & 63;
    int wid = blockIdx.x * 4 + (t >> 6);
    int n0 = (int)(((long long)wid * N_NODES) / NWAVE);
    int n1 = (int)(((long long)(wid + 1) * N_NODES) / NWAVE);
    if (n0 >= n1) return;
    float bj = b2[lane];
    float accp = 0.f;
    int cur = batch[n0];
    for (int node = n0; node < n1; ++node) {
        int k0 = rp2[node], e1 = rp2e[node];
        float acc = __half2float(g[node * HID + lane]);   // self-loop (g' = g*dinv)
        for (; k0 < e1; k0 += 64) {
            int kk = k0 + lane;
            int ev = (kk < e1) ? pk[kk] : 0;              // pad: src=0, w=+0.0
            int m = e1 - k0; if (m > 64) m = 64;
            int ng = (m + 15) >> 4;
            for (int q = 0; q < ng; ++q) {
                float vv[16], ww[16];
#pragma unroll
                for (int j = 0; j < 16; ++j) {
                    int u = __builtin_amdgcn_readlane(ev, q * 16 + j);
                    ww[j] = __half2float(__ushort_as_half((unsigned short)((unsigned)u >> 16)));
                    vv[j] = __half2float(g[(u & 0xFFFF) * HID + lane]);
                }
#pragma unroll
                for (int j = 0; j < 16; ++j) acc += vv[j] * ww[j];
            }
        }
        float h2 = fmaxf(dinv[node] * acc + bj, 0.f);
        int bb = batch[node];
        if (bb != cur) {
            atomicAdd(&pool[cur * HID + lane], accp);
            cur = bb;
            accp = 0.f;
        }
        accp += h2;
    }
    atomicAdd(&pool[cur * HID + lane], accp);
}

__device__ int lowb(const int* a, int n, int v) {
    int lo = 0, hi = n;
    while (lo < hi) { int m = (lo + hi) >> 1; if (a[m] < v) lo = m + 1; else hi = m; }
    return lo;
}

__global__ void k_out(const float* pool, const int* batch, const float* Wo,
                      const float* bo, float* out) {
    int t = blockIdx.x * blockDim.x + threadIdx.x;
    if (t < N_GRAPHS * OUT_F) {
        int gi = t / OUT_F, k = t % OUT_F;
        int c = lowb(batch, N_NODES, gi + 1) - lowb(batch, N_NODES, gi);
        float cf = fmaxf((float)c, 1.0f);
        float acc = bo[k];
        for (int f = 0; f < HID; ++f)
            acc += (pool[gi * HID + f] / cf) * Wo[f * OUT_F + k];
        out[t] = acc;
    }
}

extern "C" void kernel_launch(void* const* d_in, const int* in_sizes, int n_in,
                              void* d_out, int out_size, void* d_ws, size_t ws_size,
                              hipStream_t stream) {
    const float* x   = (const float*)d_in[0];
    const int*   ei  = (const int*)d_in[1];
    const float* ea  = (const float*)d_in[2];
    const int*   bat = (const int*)d_in[3];
    const float* W1  = (const float*)d_in[4];
    const float* b1  = (const float*)d_in[5];
    const float* W2  = (const float*)d_in[6];
    const float* b2  = (const float*)d_in[7];
    const float* Wo  = (const float*)d_in[8];
    const float* bo  = (const float*)d_in[9];
    float* out = (float*)d_out;

    const int* src = ei;
    const int* dst = ei + N_EDGES;

    // workspace layout (float units) — total 8,604,816 floats = 34.4 MB
    float* ws = (float*)d_ws;
    int*   rpB   = (int*)ws;                         // 1564 (pad 1568)
    int*   rp2   = (int*)(ws + 1568);                // 50000 (pad 50016)
    int*   rp2e  = (int*)(ws + 51584);               // 50000 (pad 50016)
    float* dinv  = ws + 101600;                      // 50000 (pad 50016)
    float* pool  = ws + 151616;                      // 3200
    int*   total = (int*)(ws + 151616);              // 1563, overlays pool, dead after bscanB
    unsigned short* cw = (unsigned short*)(ws + 154816);  // 390750 u16, dead after k_bucket
    float* p     = ws + 154816;                      // 250000, overlays cw, written after
    int2*  bkt   = (int2*)(ws + 404816);             // 3.2M int2; packed int stream after k_bsort
    __half* g    = (__half*)(ws + 6804816);          // 3.2M halves = 1.6M floats
    __half* xp   = (__half*)(ws + 8404816);          // 400000 halves = 200000 floats

    k_bhist <<<NB1, 256, 0, stream>>>(dst, cw);
    k_bscanA<<<NBKT, 256, 0, stream>>>(cw, total);
    k_bscanB<<<1, 256, 0, stream>>>(total, rpB);
    hipMemsetAsync(pool, 0, N_GRAPHS * HID * sizeof(float), stream);  // after bscanB (total overlays pool)
    k_bucket<<<NB1, 256, 0, stream>>>(src, dst, ea, cw, rpB, bkt);
    k_bsort <<<NBKT, 256, 0, stream>>>(rpB, bkt, rp2, rp2e, dinv);
    k_xprep <<<(N_NODES + 255) / 256, 256, 0, stream>>>(x, dinv, xp);
    k_p     <<<(N_NODES + 3) / 4, 256, 0, stream>>>(rp2, rp2e, (const int*)bkt, xp, dinv, p);
    k_h1g   <<<1024, 256, 0, stream>>>(p, W1, b1, W2, dinv, g);
    k_h2g   <<<NWAVE / 4, 256, 0, stream>>>(rp2, rp2e, (const int*)bkt, dinv, g, b2, bat, pool);
    k_out   <<<1, 128, 0, stream>>>(pool, bat, Wo, bo, out);
}